// Round 2
// baseline (334.178 us; speedup 1.0000x reference)
//
#include <hip/hip_runtime.h>
#include <hip/hip_bf16.h>

#define BSZ 8192
#define BTZ 8192
#define DD 64
#define NC 10
#define SHIFT2 20.0f   // log2-domain shift
#define LN2 0.69314718055994531f
#define LOG2E 1.44269504088896341f
#define NEG_BIG -1.0e30f

typedef __attribute__((ext_vector_type(8))) short bf16x8;
typedef __attribute__((ext_vector_type(4))) float f32x4;

#if defined(__has_builtin)
#if __has_builtin(__builtin_amdgcn_exp2f)
#define EXP2(x) __builtin_amdgcn_exp2f(x)
#else
#define EXP2(x) exp2f(x)
#endif
#else
#define EXP2(x) exp2f(x)
#endif

__device__ __forceinline__ unsigned short f2bf_rne(float f) {
    unsigned int u = __float_as_uint(f);
    u += 0x7FFFu + ((u >> 16) & 1u);
    return (unsigned short)(u >> 16);
}

// Kernel AB: blocks 0..511 convert src/tgt f32 -> bf16 (src pre-scaled by log2e).
// Blocks 512..543: per-tgt top2/cls/conf -> colbias (log2 domain); full label
// histogram (self-computed, L2-hot); per-class confident counts (cc_part);
// zero S + control counters; accumulate T[c][d] = sum of live tgt rows per class
// (register accumulation, wave-uniform class -> scalar branch), write T_part.
__global__ __launch_bounds__(256) void kAB(const float4* __restrict__ src4,
                                           const float4* __restrict__ tgt4,
                                           const int* __restrict__ labels,
                                           const float* __restrict__ logits,
                                           const float* __restrict__ tgtf,
                                           ushort4* __restrict__ srcb,
                                           ushort4* __restrict__ tgtb,
                                           float* __restrict__ S,
                                           float* __restrict__ colbias,
                                           float* __restrict__ cc_part,
                                           float* __restrict__ counts_g,
                                           float* __restrict__ accs,
                                           int* __restrict__ ctrl,
                                           float* __restrict__ T_part) {
    __shared__ float hist[NC];
    __shared__ float chist[NC];
    __shared__ unsigned char cls_l[256];
    __shared__ float red[4 * 640];

    int t = threadIdx.x;
    int b = blockIdx.x;

    if (b < 512) {
        int tid = b * 256 + t;    // 131072 threads cover 8192*64/4 float4s
        float4 s = src4[tid];
        ushort4 os;
        os.x = f2bf_rne(s.x * LOG2E); os.y = f2bf_rne(s.y * LOG2E);
        os.z = f2bf_rne(s.z * LOG2E); os.w = f2bf_rne(s.w * LOG2E);
        srcb[tid] = os;
        float4 v = tgt4[tid];
        ushort4 ot;
        ot.x = f2bf_rne(v.x); ot.y = f2bf_rne(v.y);
        ot.z = f2bf_rne(v.z); ot.w = f2bf_rne(v.w);
        tgtb[tid] = ot;
        return;
    }

    int lb = b - 512;             // 0..31
    int i = lb * 256 + t;         // this block's tgt rows

    if (t < NC) { hist[t] = 0.0f; chist[t] = 0.0f; }
    __syncthreads();

    // full label histogram (8192 labels, L2-hot)
    #pragma unroll
    for (int it = 0; it < 32; ++it) atomicAdd(&hist[labels[it * 256 + t]], 1.0f);

    // top-2 over 10 logits
    float m1 = -3.0e38f, m2 = -3.0e38f; int cls = 0;
    #pragma unroll
    for (int c = 0; c < NC; ++c) {
        float v = logits[i * NC + c];
        if (v > m1) { m2 = m1; m1 = v; cls = c; }
        else if (v > m2) { m2 = v; }
    }
    bool conf = (m1 - m2) >= 0.1f;
    __syncthreads();

    float cnt = hist[cls];
    bool live = conf && (cnt > 0.0f);
    colbias[i] = live ? (log2f(cnt) - SHIFT2) : NEG_BIG;
    S[i] = 0.0f;
    cls_l[t] = live ? (unsigned char)cls : (unsigned char)255;
    if (conf) atomicAdd(&chist[cls], 1.0f);
    __syncthreads();

    if (t < NC) cc_part[lb * NC + t] = chist[t];
    if (lb == 0) {
        if (t < NC) counts_g[t] = hist[t];
        if (t < 2) accs[t] = 0.0f;          // [0]=termL, [1]=term1
        if (t < 129) ctrl[t] = 0;           // rowg_cnt[128] + final_cnt
    }

    // T accumulation: lane = dim, loop over this wave's 64 rows with
    // wave-uniform class -> scalar branch into 10 register accumulators.
    int w = t >> 6, lane = t & 63;
    float Ta[NC];
    #pragma unroll
    for (int c = 0; c < NC; ++c) Ta[c] = 0.0f;
    int I0 = lb * 256;
    for (int k = 0; k < 64; ++k) {
        int li = w * 64 + k;
        int c = (int)cls_l[li];
        c = __builtin_amdgcn_readfirstlane(c);
        if (c < NC) {
            float v = tgtf[(size_t)(I0 + li) * DD + lane];
            if      (c == 0) Ta[0] += v;
            else if (c == 1) Ta[1] += v;
            else if (c == 2) Ta[2] += v;
            else if (c == 3) Ta[3] += v;
            else if (c == 4) Ta[4] += v;
            else if (c == 5) Ta[5] += v;
            else if (c == 6) Ta[6] += v;
            else if (c == 7) Ta[7] += v;
            else if (c == 8) Ta[8] += v;
            else             Ta[9] += v;
        }
    }
    #pragma unroll
    for (int c = 0; c < NC; ++c) red[w * 640 + c * 64 + lane] = Ta[c];
    __syncthreads();
    for (int idx = t; idx < 640; idx += 256)
        T_part[lb * 640 + idx] =
            red[idx] + red[640 + idx] + red[1280 + idx] + red[1920 + idx];
}

// Kernel CD: fused bf16 MFMA GEMM + exp2 row-sum, with term1 via src.T[label]
// (colchunk==0 blocks), per-rowgroup last-block termL finalize, and overall
// last-block scalar finale. No separate kD launch.
__global__ __launch_bounds__(256) void kCD(const unsigned short* __restrict__ srcb,
                                           const unsigned short* __restrict__ tgtb,
                                           const float* __restrict__ colbias,
                                           const float* __restrict__ srcf,
                                           const int* __restrict__ labels,
                                           const float* __restrict__ cc_part,
                                           const float* __restrict__ counts_g,
                                           const float* __restrict__ T_part,
                                           float* __restrict__ S,
                                           float* __restrict__ accs,
                                           int* __restrict__ ctrl,
                                           float* __restrict__ out) {
    __shared__ float lds[4][64];
    __shared__ float Tl[660];          // 10 classes x 64 dims, stride 66 (bank spread)
    __shared__ float t1red[4];
    __shared__ float ccl[NC];
    __shared__ int flag1, flag2;

    int t = threadIdx.x;
    int w = t >> 6;
    int lane = t & 63;
    int l15 = lane & 15;
    int quad = lane >> 4;
    int colchunk = blockIdx.x & 15;
    int rowg = blockIdx.x >> 4;
    int row_base = rowg * 64;

    bf16x8 a[4][2];
    #pragma unroll
    for (int mb = 0; mb < 4; ++mb) {
        const bf16x8* p = (const bf16x8*)(srcb + (size_t)(row_base + mb * 16 + l15) * DD + quad * 8);
        a[mb][0] = p[0];
        a[mb][1] = p[4];
    }

    float rs[4][4];
    #pragma unroll
    for (int mb = 0; mb < 4; ++mb)
        #pragma unroll
        for (int r = 0; r < 4; ++r) rs[mb][r] = 0.0f;

    int col0 = colchunk * 512 + w * 128;
    const bf16x8* q0 = (const bf16x8*)(tgtb + (size_t)(col0 + l15) * DD + quad * 8);
    bf16x8 b0 = q0[0];
    bf16x8 b1 = q0[4];
    float cb2 = colbias[col0 + l15];

    #pragma unroll 2
    for (int ct = 0; ct < 8; ++ct) {
        bf16x8 nb0 = b0, nb1 = b1;
        float ncb2 = cb2;
        if (ct < 7) {
            int cb = col0 + (ct + 1) * 16;
            const bf16x8* qn = (const bf16x8*)(tgtb + (size_t)(cb + l15) * DD + quad * 8);
            nb0 = qn[0];
            nb1 = qn[4];
            ncb2 = colbias[cb + l15];
        }
        #pragma unroll
        for (int mb = 0; mb < 4; ++mb) {
            f32x4 acc = {cb2, cb2, cb2, cb2};
            acc = __builtin_amdgcn_mfma_f32_16x16x32_bf16(a[mb][0], b0, acc, 0, 0, 0);
            acc = __builtin_amdgcn_mfma_f32_16x16x32_bf16(a[mb][1], b1, acc, 0, 0, 0);
            #pragma unroll
            for (int r = 0; r < 4; ++r) rs[mb][r] += EXP2(acc[r]);
        }
        b0 = nb0; b1 = nb1; cb2 = ncb2;
    }

    // row sums: reduce over 16 column-lanes per quad, cross-wave via LDS
    #pragma unroll
    for (int mb = 0; mb < 4; ++mb) {
        #pragma unroll
        for (int r = 0; r < 4; ++r) {
            float v = rs[mb][r];
            v += __shfl_xor(v, 1);
            v += __shfl_xor(v, 2);
            v += __shfl_xor(v, 4);
            v += __shfl_xor(v, 8);
            if (l15 == 0) lds[w][mb * 16 + quad * 4 + r] = v;
        }
    }
    __syncthreads();
    if (t < 64)
        atomicAdd(&S[row_base + t], lds[0][t] + lds[1][t] + lds[2][t] + lds[3][t]);

    // term1 partial for this rowgroup: sum_j src[j] . T[label_j]  (exact f32)
    if (colchunk == 0) {
        for (int idx = t; idx < 640; idx += 256) {
            float sm = 0.0f;
            #pragma unroll
            for (int p = 0; p < 32; ++p) sm += T_part[p * 640 + idx];
            Tl[(idx >> 6) * 66 + (idx & 63)] = sm;
        }
        __syncthreads();
        int r = t >> 2, dq = t & 3;
        int lab = labels[row_base + r];
        const float4* sp = (const float4*)(srcf + (size_t)(row_base + r) * DD + dq * 16);
        float part = 0.0f;
        #pragma unroll
        for (int j4 = 0; j4 < 4; ++j4) {
            float4 sv = sp[j4];
            int tb = lab * 66 + dq * 16 + j4 * 4;
            part += sv.x * Tl[tb] + sv.y * Tl[tb + 1] + sv.z * Tl[tb + 2] + sv.w * Tl[tb + 3];
        }
        #pragma unroll
        for (int m = 1; m < 64; m <<= 1) part += __shfl_xor(part, m);
        if (lane == 0) t1red[w] = part;
        __syncthreads();
        if (t == 0) atomicAdd(&accs[1], t1red[0] + t1red[1] + t1red[2] + t1red[3]);
    }

    // rowgroup finalize: the 16th-done block of each rowgroup computes termL
    // for its 64 rows from the (L2-hot, atomically-complete) S values.
    __syncthreads();          // drains each wave's outstanding atomics (vmcnt)
    __threadfence();
    if (t == 0) { int old = atomicAdd(&ctrl[rowg], 1); flag1 = (old == 15) ? 1 : 0; }
    __syncthreads();
    if (!flag1) return;

    __threadfence();          // acquire side: agent-scope full fence
    if (t < NC) {
        float s = 0.0f;
        #pragma unroll
        for (int p = 0; p < 32; ++p) s += cc_part[p * NC + t];
        ccl[t] = s;
    }
    __syncthreads();
    float val = 0.0f;
    if (t < 64) {
        float s = __hip_atomic_load(&S[row_base + t], __ATOMIC_RELAXED, __HIP_MEMORY_SCOPE_AGENT);
        float L = (log2f(s) + SHIFT2) * LN2;
        val = ccl[labels[row_base + t]] * L;
    }
    if (w == 0) {
        #pragma unroll
        for (int m = 1; m < 64; m <<= 1) val += __shfl_xor(val, m);
        if (t == 0) atomicAdd(&accs[0], val);
    }
    if (t == 0) {
        __threadfence();
        int o2 = atomicAdd(&ctrl[128], 1);
        flag2 = (o2 == 127) ? 1 : 0;
    }
    __syncthreads();
    if (flag2 && t == 0) {
        __threadfence();      // acquire side: agent-scope full fence
        float tl  = __hip_atomic_load(&accs[0], __ATOMIC_RELAXED, __HIP_MEMORY_SCOPE_AGENT);
        float t1v = __hip_atomic_load(&accs[1], __ATOMIC_RELAXED, __HIP_MEMORY_SCOPE_AGENT);
        float P = 0.0f;
        #pragma unroll
        for (int c = 0; c < NC; ++c) P += counts_g[c] * ccl[c];
        out[0] = (t1v - tl) / (-(float)BSZ * P);
    }
}

extern "C" void kernel_launch(void* const* d_in, const int* in_sizes, int n_in,
                              void* d_out, int out_size, void* d_ws, size_t ws_size,
                              hipStream_t stream) {
    const float* src    = (const float*)d_in[0];
    const int*   labels = (const int*)d_in[1];
    const float* tgt    = (const float*)d_in[2];
    const float* logits = (const float*)d_in[3];

    char* ws = (char*)d_ws;
    float* S        = (float*)(ws + 0);        // 32768 B, zeroed by kAB
    float* colbias  = (float*)(ws + 32768);    // 32768 B
    float* cc_part  = (float*)(ws + 65536);    // 1280 B
    float* counts_g = (float*)(ws + 66816);    // 40 B
    float* accs     = (float*)(ws + 66856);    // 8 B  [termL, term1]
    int*   ctrl     = (int*)(ws + 66864);      // 516 B [rowg_cnt[128], final_cnt]
    float* T_part   = (float*)(ws + 67584);    // 81920 B
    unsigned short* srcb = (unsigned short*)(ws + 163840);            // 1 MiB
    unsigned short* tgtb = (unsigned short*)(ws + 163840 + 1048576);  // 1 MiB

    kAB<<<544, 256, 0, stream>>>((const float4*)src, (const float4*)tgt, labels, logits, tgt,
                                 (ushort4*)srcb, (ushort4*)tgtb,
                                 S, colbias, cc_part, counts_g, accs, ctrl, T_part);
    kCD<<<2048, 256, 0, stream>>>(srcb, tgtb, colbias, src, labels,
                                  cc_part, counts_g, T_part, S, accs, ctrl, (float*)d_out);
}

// Round 3
// 133.990 us; speedup vs baseline: 2.4941x; 2.4941x over previous
//
#include <hip/hip_runtime.h>
#include <hip/hip_bf16.h>

#define BSZ 8192
#define BTZ 8192
#define DD 64
#define NC 10
#define SHIFT2 20.0f   // log2-domain shift
#define LN2 0.69314718055994531f
#define LOG2E 1.44269504088896341f
#define NEG_BIG -1.0e30f

typedef __attribute__((ext_vector_type(8))) short bf16x8;
typedef __attribute__((ext_vector_type(4))) float f32x4;

#if defined(__has_builtin)
#if __has_builtin(__builtin_amdgcn_exp2f)
#define EXP2(x) __builtin_amdgcn_exp2f(x)
#else
#define EXP2(x) exp2f(x)
#endif
#else
#define EXP2(x) exp2f(x)
#endif

__device__ __forceinline__ unsigned short f2bf_rne(float f) {
    unsigned int u = __float_as_uint(f);
    u += 0x7FFFu + ((u >> 16) & 1u);
    return (unsigned short)(u >> 16);
}

// Kernel AB: blocks 0..511 convert src/tgt f32 -> bf16 (src pre-scaled by log2e).
// Blocks 512..543: per-tgt top2/cls/conf -> colbias (log2 domain); full label
// histogram (self-computed, L2-hot); per-class confident counts (cc_part);
// zero S + control counters; accumulate T[c][d] = sum of live tgt rows per class
// (register accumulation, wave-uniform class -> scalar branch), write T_part.
__global__ __launch_bounds__(256) void kAB(const float4* __restrict__ src4,
                                           const float4* __restrict__ tgt4,
                                           const int* __restrict__ labels,
                                           const float* __restrict__ logits,
                                           const float* __restrict__ tgtf,
                                           ushort4* __restrict__ srcb,
                                           ushort4* __restrict__ tgtb,
                                           float* __restrict__ S,
                                           float* __restrict__ colbias,
                                           float* __restrict__ cc_part,
                                           float* __restrict__ counts_g,
                                           float* __restrict__ accs,
                                           int* __restrict__ ctrl,
                                           float* __restrict__ T_part) {
    __shared__ float hist[NC];
    __shared__ float chist[NC];
    __shared__ unsigned char cls_l[256];
    __shared__ float red[4 * 640];

    int t = threadIdx.x;
    int b = blockIdx.x;

    if (b < 512) {
        int tid = b * 256 + t;    // 131072 threads cover 8192*64/4 float4s
        float4 s = src4[tid];
        ushort4 os;
        os.x = f2bf_rne(s.x * LOG2E); os.y = f2bf_rne(s.y * LOG2E);
        os.z = f2bf_rne(s.z * LOG2E); os.w = f2bf_rne(s.w * LOG2E);
        srcb[tid] = os;
        float4 v = tgt4[tid];
        ushort4 ot;
        ot.x = f2bf_rne(v.x); ot.y = f2bf_rne(v.y);
        ot.z = f2bf_rne(v.z); ot.w = f2bf_rne(v.w);
        tgtb[tid] = ot;
        return;
    }

    int lb = b - 512;             // 0..31
    int i = lb * 256 + t;         // this block's tgt rows

    if (t < NC) { hist[t] = 0.0f; chist[t] = 0.0f; }
    __syncthreads();

    // full label histogram (8192 labels, L2-hot)
    #pragma unroll
    for (int it = 0; it < 32; ++it) atomicAdd(&hist[labels[it * 256 + t]], 1.0f);

    // top-2 over 10 logits
    float m1 = -3.0e38f, m2 = -3.0e38f; int cls = 0;
    #pragma unroll
    for (int c = 0; c < NC; ++c) {
        float v = logits[i * NC + c];
        if (v > m1) { m2 = m1; m1 = v; cls = c; }
        else if (v > m2) { m2 = v; }
    }
    bool conf = (m1 - m2) >= 0.1f;
    __syncthreads();

    float cnt = hist[cls];
    bool live = conf && (cnt > 0.0f);
    colbias[i] = live ? (log2f(cnt) - SHIFT2) : NEG_BIG;
    S[i] = 0.0f;
    cls_l[t] = live ? (unsigned char)cls : (unsigned char)255;
    if (conf) atomicAdd(&chist[cls], 1.0f);
    __syncthreads();

    if (t < NC) cc_part[lb * NC + t] = chist[t];
    if (lb == 0) {
        if (t < NC) counts_g[t] = hist[t];
        if (t < 2) accs[t] = 0.0f;          // [0]=termL, [1]=term1
        if (t < 129) ctrl[t] = 0;           // rowg_cnt[128] + final_cnt
    }

    // T accumulation: lane = dim, loop over this wave's 64 rows with
    // wave-uniform class -> scalar branch into 10 register accumulators.
    int w = t >> 6, lane = t & 63;
    float Ta[NC];
    #pragma unroll
    for (int c = 0; c < NC; ++c) Ta[c] = 0.0f;
    int I0 = lb * 256;
    for (int k = 0; k < 64; ++k) {
        int li = w * 64 + k;
        int c = (int)cls_l[li];
        c = __builtin_amdgcn_readfirstlane(c);
        if (c < NC) {
            float v = tgtf[(size_t)(I0 + li) * DD + lane];
            if      (c == 0) Ta[0] += v;
            else if (c == 1) Ta[1] += v;
            else if (c == 2) Ta[2] += v;
            else if (c == 3) Ta[3] += v;
            else if (c == 4) Ta[4] += v;
            else if (c == 5) Ta[5] += v;
            else if (c == 6) Ta[6] += v;
            else if (c == 7) Ta[7] += v;
            else if (c == 8) Ta[8] += v;
            else             Ta[9] += v;
        }
    }
    #pragma unroll
    for (int c = 0; c < NC; ++c) red[w * 640 + c * 64 + lane] = Ta[c];
    __syncthreads();
    for (int idx = t; idx < 640; idx += 256)
        T_part[lb * 640 + idx] =
            red[idx] + red[640 + idx] + red[1280 + idx] + red[1920 + idx];
}

// Kernel CD: fused bf16 MFMA GEMM + exp2 row-sum, with term1 via src.T[label]
// (colchunk==0 blocks), per-rowgroup last-block termL finalize, and overall
// last-block scalar finale. No separate kD launch.
//
// Coherence design (no __threadfence -- agent fences emit buffer_wbl2/buffer_inv,
// a full per-XCD L2 writeback+invalidate; doing that in 2048 blocks cost 245us):
// all cross-block data flows through device-scope atomic RMWs (performed at the
// device coherence point) and is read back with agent-scope atomic loads (which
// bypass L1/L2 by encoding). The only ordering needed is vmcnt completion before
// the ctrl counter bump; __syncthreads already emits s_waitcnt vmcnt(0) before
// s_barrier, and the one unbarriered spot uses an explicit s_waitcnt.
__global__ __launch_bounds__(256) void kCD(const unsigned short* __restrict__ srcb,
                                           const unsigned short* __restrict__ tgtb,
                                           const float* __restrict__ colbias,
                                           const float* __restrict__ srcf,
                                           const int* __restrict__ labels,
                                           const float* __restrict__ cc_part,
                                           const float* __restrict__ counts_g,
                                           const float* __restrict__ T_part,
                                           float* __restrict__ S,
                                           float* __restrict__ accs,
                                           int* __restrict__ ctrl,
                                           float* __restrict__ out) {
    __shared__ float lds[4][64];
    __shared__ float Tl[660];          // 10 classes x 64 dims, stride 66 (bank spread)
    __shared__ float t1red[4];
    __shared__ float ccl[NC];
    __shared__ int flag1, flag2;

    int t = threadIdx.x;
    int w = t >> 6;
    int lane = t & 63;
    int l15 = lane & 15;
    int quad = lane >> 4;
    int colchunk = blockIdx.x & 15;
    int rowg = blockIdx.x >> 4;
    int row_base = rowg * 64;

    bf16x8 a[4][2];
    #pragma unroll
    for (int mb = 0; mb < 4; ++mb) {
        const bf16x8* p = (const bf16x8*)(srcb + (size_t)(row_base + mb * 16 + l15) * DD + quad * 8);
        a[mb][0] = p[0];
        a[mb][1] = p[4];
    }

    float rs[4][4];
    #pragma unroll
    for (int mb = 0; mb < 4; ++mb)
        #pragma unroll
        for (int r = 0; r < 4; ++r) rs[mb][r] = 0.0f;

    int col0 = colchunk * 512 + w * 128;
    const bf16x8* q0 = (const bf16x8*)(tgtb + (size_t)(col0 + l15) * DD + quad * 8);
    bf16x8 b0 = q0[0];
    bf16x8 b1 = q0[4];
    float cb2 = colbias[col0 + l15];

    #pragma unroll 2
    for (int ct = 0; ct < 8; ++ct) {
        bf16x8 nb0 = b0, nb1 = b1;
        float ncb2 = cb2;
        if (ct < 7) {
            int cb = col0 + (ct + 1) * 16;
            const bf16x8* qn = (const bf16x8*)(tgtb + (size_t)(cb + l15) * DD + quad * 8);
            nb0 = qn[0];
            nb1 = qn[4];
            ncb2 = colbias[cb + l15];
        }
        #pragma unroll
        for (int mb = 0; mb < 4; ++mb) {
            f32x4 acc = {cb2, cb2, cb2, cb2};
            acc = __builtin_amdgcn_mfma_f32_16x16x32_bf16(a[mb][0], b0, acc, 0, 0, 0);
            acc = __builtin_amdgcn_mfma_f32_16x16x32_bf16(a[mb][1], b1, acc, 0, 0, 0);
            #pragma unroll
            for (int r = 0; r < 4; ++r) rs[mb][r] += EXP2(acc[r]);
        }
        b0 = nb0; b1 = nb1; cb2 = ncb2;
    }

    // row sums: reduce over 16 column-lanes per quad, cross-wave via LDS
    #pragma unroll
    for (int mb = 0; mb < 4; ++mb) {
        #pragma unroll
        for (int r = 0; r < 4; ++r) {
            float v = rs[mb][r];
            v += __shfl_xor(v, 1);
            v += __shfl_xor(v, 2);
            v += __shfl_xor(v, 4);
            v += __shfl_xor(v, 8);
            if (l15 == 0) lds[w][mb * 16 + quad * 4 + r] = v;
        }
    }
    __syncthreads();
    if (t < 64)
        atomicAdd(&S[row_base + t], lds[0][t] + lds[1][t] + lds[2][t] + lds[3][t]);

    // term1 partial for this rowgroup: sum_j src[j] . T[label_j]  (exact f32)
    if (colchunk == 0) {
        for (int idx = t; idx < 640; idx += 256) {
            float sm = 0.0f;
            #pragma unroll
            for (int p = 0; p < 32; ++p) sm += T_part[p * 640 + idx];
            Tl[(idx >> 6) * 66 + (idx & 63)] = sm;
        }
        __syncthreads();
        int r = t >> 2, dq = t & 3;
        int lab = labels[row_base + r];
        const float4* sp = (const float4*)(srcf + (size_t)(row_base + r) * DD + dq * 16);
        float part = 0.0f;
        #pragma unroll
        for (int j4 = 0; j4 < 4; ++j4) {
            float4 sv = sp[j4];
            int tb = lab * 66 + dq * 16 + j4 * 4;
            part += sv.x * Tl[tb] + sv.y * Tl[tb + 1] + sv.z * Tl[tb + 2] + sv.w * Tl[tb + 3];
        }
        #pragma unroll
        for (int m = 1; m < 64; m <<= 1) part += __shfl_xor(part, m);
        if (lane == 0) t1red[w] = part;
        __syncthreads();
        if (t == 0) atomicAdd(&accs[1], t1red[0] + t1red[1] + t1red[2] + t1red[3]);
    }

    // rowgroup finalize: the 16th-done block of each rowgroup computes termL
    // for its 64 rows from the (atomically-complete) S values.
    __syncthreads();   // emits s_waitcnt vmcnt(0) before s_barrier: S/accs atomics complete
    if (t == 0) { int old = atomicAdd(&ctrl[rowg], 1); flag1 = (old == 15) ? 1 : 0; }
    __syncthreads();
    if (!flag1) return;

    if (t < NC) {
        float s = 0.0f;
        #pragma unroll
        for (int p = 0; p < 32; ++p) s += cc_part[p * NC + t];
        ccl[t] = s;
    }
    __syncthreads();
    float val = 0.0f;
    if (t < 64) {
        float s = __hip_atomic_load(&S[row_base + t], __ATOMIC_RELAXED, __HIP_MEMORY_SCOPE_AGENT);
        float L = (log2f(s) + SHIFT2) * LN2;
        val = ccl[labels[row_base + t]] * L;
    }
    if (w == 0) {
        #pragma unroll
        for (int m = 1; m < 64; m <<= 1) val += __shfl_xor(val, m);
        if (t == 0) atomicAdd(&accs[0], val);
    }
    if (t == 0) {
        asm volatile("s_waitcnt vmcnt(0)" ::: "memory");  // accs add complete before count bump
        int o2 = atomicAdd(&ctrl[128], 1);
        flag2 = (o2 == 127) ? 1 : 0;
    }
    __syncthreads();
    if (flag2 && t == 0) {
        float tl  = __hip_atomic_load(&accs[0], __ATOMIC_RELAXED, __HIP_MEMORY_SCOPE_AGENT);
        float t1v = __hip_atomic_load(&accs[1], __ATOMIC_RELAXED, __HIP_MEMORY_SCOPE_AGENT);
        float P = 0.0f;
        #pragma unroll
        for (int c = 0; c < NC; ++c) P += counts_g[c] * ccl[c];
        out[0] = (t1v - tl) / (-(float)BSZ * P);
    }
}

extern "C" void kernel_launch(void* const* d_in, const int* in_sizes, int n_in,
                              void* d_out, int out_size, void* d_ws, size_t ws_size,
                              hipStream_t stream) {
    const float* src    = (const float*)d_in[0];
    const int*   labels = (const int*)d_in[1];
    const float* tgt    = (const float*)d_in[2];
    const float* logits = (const float*)d_in[3];

    char* ws = (char*)d_ws;
    float* S        = (float*)(ws + 0);        // 32768 B, zeroed by kAB
    float* colbias  = (float*)(ws + 32768);    // 32768 B
    float* cc_part  = (float*)(ws + 65536);    // 1280 B
    float* counts_g = (float*)(ws + 66816);    // 40 B
    float* accs     = (float*)(ws + 66856);    // 8 B  [termL, term1]
    int*   ctrl     = (int*)(ws + 66864);      // 516 B [rowg_cnt[128], final_cnt]
    float* T_part   = (float*)(ws + 67584);    // 81920 B
    unsigned short* srcb = (unsigned short*)(ws + 163840);            // 1 MiB
    unsigned short* tgtb = (unsigned short*)(ws + 163840 + 1048576);  // 1 MiB

    kAB<<<544, 256, 0, stream>>>((const float4*)src, (const float4*)tgt, labels, logits, tgt,
                                 (ushort4*)srcb, (ushort4*)tgtb,
                                 S, colbias, cc_part, counts_g, accs, ctrl, T_part);
    kCD<<<2048, 256, 0, stream>>>(srcb, tgtb, colbias, src, labels,
                                  cc_part, counts_g, T_part, S, accs, ctrl, (float*)d_out);
}